// Round 9
// baseline (19.960 us; speedup 1.0000x reference)
//
#include <hip/hip_runtime.h>

#define BB 16
#define NN 65536
#define KK 64
#define TPB 256
#define EPB 1024                  // 4 elems/thread (one float4)
#define NBLK ((BB * NN) / EPB)    // 1024 blocks = 4/CU, all co-resident

__device__ __forceinline__ float readlane_f(float v, int lane) {
    return __uint_as_float((unsigned)__builtin_amdgcn_readlane((int)__float_as_uint(v), lane));
}

// 8-lag group load: 8 independent dwordx4 gathers (SGPR base, shared voffset).
#define LOADG(BUF, BASE)                                                      \
    do {                                                                      \
        _Pragma("unroll")                                                     \
        for (int mi = 0; mi < 8; ++mi) {                                      \
            const int jj = __builtin_amdgcn_readlane(jv, (BASE) + mi);        \
            __builtin_memcpy(&BUF[mi], xr + (e0 - jj), 16);                   \
        }                                                                     \
    } while (0)

// 8-lag group consume: f32 FMAs, flushed to f64 accumulators.
#define FMAG(BUF, BASE)                                                       \
    do {                                                                      \
        float gx = 0.f, gy = 0.f, gz = 0.f, gw = 0.f;                         \
        _Pragma("unroll")                                                     \
        for (int mi = 0; mi < 8; ++mi) {                                      \
            const float wm = readlane_f(wv, (BASE) + mi);                     \
            gx = fmaf(xt.x - BUF[mi].x, wm, gx);                              \
            gy = fmaf(xt.y - BUF[mi].y, wm, gy);                              \
            gz = fmaf(xt.z - BUF[mi].z, wm, gz);                              \
            gw = fmaf(xt.w - BUF[mi].w, wm, gw);                              \
        }                                                                     \
        a0 += (double)gx; a1 += (double)gy;                                   \
        a2 += (double)gz; a3 += (double)gw;                                   \
    } while (0)

__global__ __launch_bounds__(TPB, 4) void frac_deriv_kernel(
    const float* __restrict__ x,
    const float* __restrict__ loc,
    const float* __restrict__ scale,
    const float* __restrict__ eps,
    const int* __restrict__ lags,
    float* __restrict__ out)
{
    __shared__ int   js_raw[KK];
    __shared__ float ws_raw[KK];
    __shared__ int   js[KK];
    __shared__ float ws[KK];

    const int tid  = threadIdx.x;
    const int lane = tid & 63;

    // Bijective XCD swizzle (128 blocks/XCD = 2 rows) + heavy-first within XCD.
    const int bid = blockIdx.x;
    const int swz = (bid & 7) * (NBLK / 8) + (bid >> 3);
    const int b   = swz >> 6;
    const int q   = 63 - (swz & 63);     // heavy-first: large T dispatched first
    const int T   = q * EPB;

    const float* __restrict__ xr = x + (size_t)b * NN;
    const int e0 = T + 4 * tid;
    float4 xt;
    __builtin_memcpy(&xt, xr + e0, 16);  // issue early; hides under prologue

    // --- Prologue: wave 0 computes f64 weights and rank-sorts lags (measured free).
    if (tid < KK) {
        double s  = (double)scale[0];
        double sp = (s > 20.0) ? s : log1p(exp(s));
        double a  = (double)loc[0] + sp * (double)eps[0];
        a = fmin(fmax(a, 0.01), 0.99);
        double c = a * exp(-lgamma(1.0 - a)) * ((double)(NN - 1) / (double)KK);
        int j = lags[tid];
        j = (j < 1) ? 1 : ((j > NN - 1) ? NN - 1 : j);
        js_raw[tid] = j;
        ws_raw[tid] = (float)(c * exp(-(a + 1.0) * log((double)j)));
    }
    __syncthreads();
    if (tid < KK) {
        const int j = js_raw[tid];
        int rank = 0;
        for (int k = 0; k < KK; ++k) {
            const int jk = js_raw[k];
            rank += (int)((jk < j) || (jk == j && k < tid));
        }
        js[rank] = j;
        ws[rank] = ws_raw[tid];
    }
    __syncthreads();

    const int   jv = js[lane];
    const float wv = ws[lane];
    const int cf = __popcll(__ballot(jv <= T));             // fully-valid prefix
    const int cp = __popcll(__ballot(jv <= T + (EPB - 1))); // incl. straddle
    const int cf8  = cf & ~7;
    const int ngrp = cf8 >> 3;

    double a0 = 0.0, a1 = 0.0, a2 = 0.0, a3 = 0.0;

    // --- Double-buffered pipeline: while FMA-ing group g, group g+1's 8 gathers
    //     stay in flight — the wave never drains vmcnt to 0 between groups.
    float4 A[8], Bv[8];
    int g = 0;
    if (ngrp > 0) LOADG(A, 0);
    for (; g + 2 < ngrp; g += 2) {
        LOADG(Bv, (g + 1) * 8);
        FMAG(A, g * 8);
        LOADG(A, (g + 2) * 8);
        FMAG(Bv, (g + 1) * 8);
    }
    if (g < ngrp) {
        if (g + 1 < ngrp) {
            LOADG(Bv, (g + 1) * 8);
            FMAG(A, g * 8);
            FMAG(Bv, (g + 1) * 8);
        } else {
            FMAG(A, g * 8);
        }
    }

    // --- Tail: remaining valid + straddle lags, per-element masked clamp.
    for (int m = cf8; m < cp; ++m) {
        const int   jj = __builtin_amdgcn_readlane(jv, m);
        const float w  = readlane_f(wv, m);
        const int d0 = e0 - jj;
        const float g0 = xr[(d0     < 0) ? 0 : d0];
        const float g1 = xr[(d0 + 1 < 0) ? 0 : d0 + 1];
        const float g2 = xr[(d0 + 2 < 0) ? 0 : d0 + 2];
        const float g3 = xr[(d0 + 3 < 0) ? 0 : d0 + 3];
        a0 += (d0     >= 0) ? (double)((xt.x - g0) * w) : 0.0;
        a1 += (d0 + 1 >= 0) ? (double)((xt.y - g1) * w) : 0.0;
        a2 += (d0 + 2 >= 0) ? (double)((xt.z - g2) * w) : 0.0;
        a3 += (d0 + 3 >= 0) ? (double)((xt.w - g3) * w) : 0.0;
    }

    float4 r = make_float4((float)a0, (float)a1, (float)a2, (float)a3);
    __builtin_memcpy(out + (size_t)b * NN + e0, &r, 16);
}

extern "C" void kernel_launch(void* const* d_in, const int* in_sizes, int n_in,
                              void* d_out, int out_size, void* d_ws, size_t ws_size,
                              hipStream_t stream) {
    const float* x     = (const float*)d_in[0];
    const float* loc   = (const float*)d_in[1];
    const float* scale = (const float*)d_in[2];
    const float* eps   = (const float*)d_in[3];
    const int*   lags  = (const int*)d_in[4];
    float* out = (float*)d_out;

    frac_deriv_kernel<<<NBLK, TPB, 0, stream>>>(x, loc, scale, eps, lags, out);
}